// Round 1
// baseline (610.833 us; speedup 1.0000x reference)
//
#include <hip/hip_runtime.h>
#include <hip/hip_cooperative_groups.h>
#include <math.h>

namespace cg = cooperative_groups;

#define RANK 128
#define INV_T 20.0f      // 1 / 0.05
#define EPS_ARG 1e-7f
#define NBLK 1024        // 4 blocks/CU * 256 CU -> co-resident for cooperative launch
#define NTHR 256

// online-softmax combine: state (m, z, w); s is a plain sum
__device__ inline void comb(float& m, float& z, float& w, float& s,
                            float m2, float z2, float w2, float s2) {
    float mn = fmaxf(m, m2);
    float a = (m  == mn) ? 1.0f : __expf(m  - mn);
    float b = (m2 == mn) ? 1.0f : __expf(m2 - mn);
    z = z * a + z2 * b;
    w = w * a + w2 * b;
    m = mn;
    s += s2;
}

__global__ __launch_bounds__(NTHR, 4)
void fused(const float* __restrict__ emb, const int* __restrict__ lca,
           const float* __restrict__ scale, const float4* __restrict__ leaves,
           float* __restrict__ D, int nLeaves,
           const int* __restrict__ li, const int* __restrict__ ri,
           const float* __restrict__ sims, float4* __restrict__ partials,
           int P, float* __restrict__ out)
{
    cg::grid_group grid = cg::this_grid();
    __shared__ float4 se1[RANK / 4];
    __shared__ float  snx[2];
    __shared__ float4 sp[NTHR / 64];
    int t = threadIdx.x;

    // ---- per-block e1 normalization (512B broadcast read, 1 half-wave) ----
    if (t < 32) {
        float4 v = ((const float4*)(emb + (size_t)lca[0] * RANK))[t];
        float sq = v.x * v.x + v.y * v.y + v.z * v.z + v.w * v.w;
#pragma unroll
        for (int o = 16; o; o >>= 1) sq += __shfl_down(sq, o, 32);
        sq = __shfl(sq, 0, 32);
        float bn = sqrtf(sq);
        float s = fminf(fmaxf(scale[0], 0.01f), 1.0f - 0.001f);
        float k = s / fmaxf(bn, 1e-12f);
        float4 e; e.x = v.x * k; e.y = v.y * k; e.z = v.z * k; e.w = v.w * k;
        se1[t] = e;
        float sq2 = e.x * e.x + e.y * e.y + e.z * e.z + e.w * e.w;
#pragma unroll
        for (int o = 16; o; o >>= 1) sq2 += __shfl_down(sq2, o, 32);
        if (t == 0) {
            snx[0] = sq2;                  // nx
            snx[1] = 1.0f / (1.0f - sq2);  // 1/(1-nx)
        }
    }
    __syncthreads();

    // ---- phase 1: leaf distances. 4 leaves/wave-iter (2 loads in flight/lane) ----
    {
        int lane = t & 63, wid = t >> 6;
        int l31 = lane & 31, half = lane >> 5;
        int gw = blockIdx.x * (NTHR >> 6) + wid;
        int nw = NBLK * (NTHR >> 6);
        float nx = snx[0], invdx = snx[1];
        float4 e = se1[l31];
        for (int jj = gw; 4 * jj < nLeaves; jj += nw) {
            int j0 = 4 * jj + half;       // half-wave handles j0 and j0+2
            int j1 = j0 + 2;
            bool v0 = j0 < nLeaves, v1 = j1 < nLeaves;
            float4 y0 = make_float4(0.f, 0.f, 0.f, 0.f);
            float4 y1 = make_float4(0.f, 0.f, 0.f, 0.f);
            if (v0) y0 = leaves[(size_t)j0 * (RANK / 4) + l31];
            if (v1) y1 = leaves[(size_t)j1 * (RANK / 4) + l31];
            float dot0 = y0.x * e.x + y0.y * e.y + y0.z * e.z + y0.w * e.w;
            float ny0  = y0.x * y0.x + y0.y * y0.y + y0.z * y0.z + y0.w * y0.w;
            float dot1 = y1.x * e.x + y1.y * e.y + y1.z * e.z + y1.w * e.w;
            float ny1  = y1.x * y1.x + y1.y * y1.y + y1.z * y1.z + y1.w * y1.w;
#pragma unroll
            for (int o = 16; o; o >>= 1) {
                dot0 += __shfl_down(dot0, o, 32);
                ny0  += __shfl_down(ny0, o, 32);
                dot1 += __shfl_down(dot1, o, 32);
                ny1  += __shfl_down(ny1, o, 32);
            }
            if (l31 == 0) {
                if (v0) {
                    float sq  = nx + ny0 - 2.0f * dot0;
                    float arg = 1.0f + 2.0f * sq * invdx / (1.0f - ny0);
                    D[j0] = acoshf(fmaxf(arg, 1.0f + EPS_ARG));
                }
                if (v1) {
                    float sq  = nx + ny1 - 2.0f * dot1;
                    float arg = 1.0f + 2.0f * sq * invdx / (1.0f - ny1);
                    D[j1] = acoshf(fmaxf(arg, 1.0f + EPS_ARG));
                }
            }
        }
    }
    __threadfence();   // agent-scope release: make D visible across XCDs
    grid.sync();

    // ---- phase 2: fused pair online-softmax partials ----
    float m = -INFINITY, z = 0.0f, w = 0.0f, s = 0.0f;
    {
        int tid = blockIdx.x * NTHR + t;
        const int nthreads = NBLK * NTHR;
        int P4 = P >> 2;
        const int4*   li4 = (const int4*)li;
        const int4*   ri4 = (const int4*)ri;
        const float4* s4p = (const float4*)sims;
        for (int i = tid; i < P4; i += nthreads) {
            int4 l = li4[i], r = ri4[i];
            float4 sv = s4p[i];
            float a0 = D[l.x], b0 = D[r.x];
            float a1 = D[l.y], b1 = D[r.y];
            float a2 = D[l.z], b2 = D[r.z];
            float a3 = D[l.w], b3 = D[r.w];
            float t0 = (a0 + b0) * INV_T, t1 = (a1 + b1) * INV_T;
            float t2 = (a2 + b2) * INV_T, t3 = (a3 + b3) * INV_T;
#define STEP(tp, svv)                                                  \
            if (tp <= m) { float e = __expf(tp - m); z += e; w = fmaf(svv, e, w); } \
            else { float rr = __expf(m - tp); z = fmaf(z, rr, 1.0f); w = fmaf(w, rr, svv); m = tp; } \
            s += svv;
            STEP(t0, sv.x) STEP(t1, sv.y) STEP(t2, sv.z) STEP(t3, sv.w)
        }
        int tail0 = P4 << 2;
        for (int p = tail0 + tid; p < P; p += nthreads) {
            float tp = (D[li[p]] + D[ri[p]]) * INV_T;
            float svv = sims[p];
            STEP(tp, svv)
        }
#undef STEP
    }
#pragma unroll
    for (int o = 32; o; o >>= 1) {
        float m2 = __shfl_xor(m, o), z2 = __shfl_xor(z, o);
        float w2 = __shfl_xor(w, o), s2 = __shfl_xor(s, o);
        comb(m, z, w, s, m2, z2, w2, s2);
    }
    {
        int lane = t & 63, wid = t >> 6;
        if (lane == 0) sp[wid] = make_float4(m, z, w, s);
        __syncthreads();
        if (t == 0) {
            for (int i = 1; i < (NTHR >> 6); i++) {
                float4 q = sp[i];
                comb(m, z, w, s, q.x, q.y, q.z, q.w);
            }
            partials[blockIdx.x] = make_float4(m, z, w, s);
        }
    }
    __threadfence();   // make partials visible across XCDs
    grid.sync();

    // ---- phase 3: block 0 reduces per-block partials ----
    if (blockIdx.x == 0) {
        float fm = -INFINITY, fz = 0.0f, fw = 0.0f, fs = 0.0f;
        for (int i = t; i < NBLK; i += NTHR) {
            float4 q = partials[i];
            comb(fm, fz, fw, fs, q.x, q.y, q.z, q.w);
        }
#pragma unroll
        for (int o = 32; o; o >>= 1) {
            float m2 = __shfl_xor(fm, o), z2 = __shfl_xor(fz, o);
            float w2 = __shfl_xor(fw, o), s2 = __shfl_xor(fs, o);
            comb(fm, fz, fw, fs, m2, z2, w2, s2);
        }
        int lane = t & 63, wid = t >> 6;
        __syncthreads();   // sp reuse: everyone past previous reads
        if (lane == 0) sp[wid] = make_float4(fm, fz, fw, fs);
        __syncthreads();
        if (t == 0) {
            for (int i = 1; i < (NTHR >> 6); i++) {
                float4 q = sp[i];
                comb(fm, fz, fw, fs, q.x, q.y, q.z, q.w);
            }
            out[0] = fs - fw / fz;
        }
    }
}

extern "C" void kernel_launch(void* const* d_in, const int* in_sizes, int n_in,
                              void* d_out, int out_size, void* d_ws, size_t ws_size,
                              hipStream_t stream) {
    const float* emb    = (const float*)d_in[4];
    const int*   lca    = (const int*)d_in[0];
    const float* scale  = (const float*)d_in[6];
    const float4* leaves = (const float4*)d_in[5];
    const int*   li     = (const int*)d_in[1];
    const int*   ri     = (const int*)d_in[2];
    const float* sims   = (const float*)d_in[3];
    float* out = (float*)d_out;

    int P       = in_sizes[1];
    int nLeaves = in_sizes[5] / RANK;

    char* ws = (char*)d_ws;
    float*  D        = (float*)ws;
    size_t  poff     = (((size_t)nLeaves * sizeof(float) + 1023) / 1024) * 1024;
    float4* partials = (float4*)(ws + poff);

    void* args[] = { (void*)&emb, (void*)&lca, (void*)&scale, (void*)&leaves,
                     (void*)&D, (void*)&nLeaves, (void*)&li, (void*)&ri,
                     (void*)&sims, (void*)&partials, (void*)&P, (void*)&out };
    hipLaunchCooperativeKernel((const void*)fused, dim3(NBLK), dim3(NTHR),
                               args, 0, stream);
}

// Round 2
// 209.660 us; speedup vs baseline: 2.9134x; 2.9134x over previous
//
#include <hip/hip_runtime.h>
#include <math.h>

#define RANK 128
#define INV_T 20.0f      // 1 / 0.05
#define EPS_ARG 1e-7f
#define NBLK_PAIR 512
#define NTHR 256

// online-softmax combine: state (m, z, w); s is a plain sum
__device__ inline void comb(float& m, float& z, float& w, float& s,
                            float m2, float z2, float w2, float s2) {
    float mn = fmaxf(m, m2);
    float a = (m  == mn) ? 1.0f : __expf(m  - mn);
    float b = (m2 == mn) ? 1.0f : __expf(m2 - mn);
    z = z * a + z2 * b;
    w = w * a + w2 * b;
    m = mn;
    s += s2;
}

// ---------------- k_leaf: e1 prep (per-block, redundant) + per-leaf distance ----
__global__ void k_leaf(const float* __restrict__ emb, const int* __restrict__ lca,
                       const float* __restrict__ scale,
                       const float4* __restrict__ leaves,
                       float* __restrict__ D, int nLeaves,
                       unsigned int* __restrict__ counter) {
    __shared__ float4 se1[RANK / 4];
    __shared__ float  snx[2];
    int t = threadIdx.x;

    // zero the last-block-done counter for k_pair (visible after kernel boundary)
    if (blockIdx.x == 0 && t == 0) *counter = 0u;

    // ---- per-block e1 normalization (512B broadcast read, 1 half-wave) ----
    if (t < 32) {
        float4 v = ((const float4*)(emb + (size_t)lca[0] * RANK))[t];
        float sq = v.x * v.x + v.y * v.y + v.z * v.z + v.w * v.w;
#pragma unroll
        for (int o = 16; o; o >>= 1) sq += __shfl_down(sq, o, 32);
        sq = __shfl(sq, 0, 32);
        float bn = sqrtf(sq);
        float s = fminf(fmaxf(scale[0], 0.01f), 1.0f - 0.001f);
        float k = s / fmaxf(bn, 1e-12f);
        float4 e; e.x = v.x * k; e.y = v.y * k; e.z = v.z * k; e.w = v.w * k;
        se1[t] = e;
        float sq2 = e.x * e.x + e.y * e.y + e.z * e.z + e.w * e.w;
#pragma unroll
        for (int o = 16; o; o >>= 1) sq2 += __shfl_down(sq2, o, 32);
        if (t == 0) {
            snx[0] = sq2;                  // nx
            snx[1] = 1.0f / (1.0f - sq2);  // 1/(1-nx)
        }
    }
    __syncthreads();

    // ---- leaf distances: one wave = 2 leaves, float4/lane coalesced ----
    int lane = t & 63, wid = t >> 6;
    int l31 = lane & 31, half = lane >> 5;
    int wavesPerBlock = NTHR >> 6;
    int gw = blockIdx.x * wavesPerBlock + wid;
    int nw = gridDim.x * wavesPerBlock;
    float nx = snx[0], invdx = snx[1];
    float4 e = se1[l31];
    for (int jj = gw; 2 * jj < nLeaves; jj += nw) {
        int j = 2 * jj + half;
        float dot = 0.0f, ny = 0.0f;
        if (j < nLeaves) {
            float4 y = leaves[(size_t)j * (RANK / 4) + l31];   // 1KB/wave
            dot = y.x * e.x + y.y * e.y + y.z * e.z + y.w * e.w;
            ny  = y.x * y.x + y.y * y.y + y.z * y.z + y.w * y.w;
        }
#pragma unroll
        for (int o = 16; o; o >>= 1) {
            dot += __shfl_down(dot, o, 32);
            ny  += __shfl_down(ny, o, 32);
        }
        if (l31 == 0 && j < nLeaves) {
            float sq  = nx + ny - 2.0f * dot;                  // ||x-y||^2
            float arg = 1.0f + 2.0f * sq * invdx / (1.0f - ny);
            arg = fmaxf(arg, 1.0f + EPS_ARG);
            D[j] = acoshf(arg);
        }
    }
}

// ---- k_pair: fused pair online-softmax partials + last-block final reduce ----
__global__ void k_pair(const int* __restrict__ li, const int* __restrict__ ri,
                       const float* __restrict__ sims, const float* __restrict__ D,
                       float4* __restrict__ partials, int P,
                       unsigned int* __restrict__ counter, float* __restrict__ out) {
    float m = -INFINITY, z = 0.0f, w = 0.0f, s = 0.0f;
    int tid = blockIdx.x * NTHR + threadIdx.x;
    int nthreads = gridDim.x * NTHR;
    int P4 = P >> 2;
    const int4*   li4 = (const int4*)li;
    const int4*   ri4 = (const int4*)ri;
    const float4* s4p = (const float4*)sims;
    for (int i = tid; i < P4; i += nthreads) {
        int4 l = li4[i], r = ri4[i];
        float4 sv = s4p[i];
        float a0 = D[l.x], b0 = D[r.x];
        float a1 = D[l.y], b1 = D[r.y];
        float a2 = D[l.z], b2 = D[r.z];
        float a3 = D[l.w], b3 = D[r.w];
        float t0 = (a0 + b0) * INV_T, t1 = (a1 + b1) * INV_T;
        float t2 = (a2 + b2) * INV_T, t3 = (a3 + b3) * INV_T;
#define STEP(tp, svv)                                                  \
        if (tp <= m) { float e = __expf(tp - m); z += e; w = fmaf(svv, e, w); } \
        else { float rr = __expf(m - tp); z = fmaf(z, rr, 1.0f); w = fmaf(w, rr, svv); m = tp; } \
        s += svv;
        STEP(t0, sv.x) STEP(t1, sv.y) STEP(t2, sv.z) STEP(t3, sv.w)
    }
    int tail0 = P4 << 2;
    for (int p = tail0 + tid; p < P; p += nthreads) {
        float tp = (D[li[p]] + D[ri[p]]) * INV_T;
        float svv = sims[p];
        STEP(tp, svv)
    }
#undef STEP
#pragma unroll
    for (int o = 32; o; o >>= 1) {
        float m2 = __shfl_xor(m, o), z2 = __shfl_xor(z, o);
        float w2 = __shfl_xor(w, o), s2 = __shfl_xor(s, o);
        comb(m, z, w, s, m2, z2, w2, s2);
    }
    __shared__ float4 sp[NTHR / 64];
    __shared__ bool isLast;
    int lane = threadIdx.x & 63, wid = threadIdx.x >> 6;
    if (lane == 0) sp[wid] = make_float4(m, z, w, s);
    __syncthreads();
    if (threadIdx.x == 0) {
        for (int i = 1; i < (NTHR >> 6); i++) {
            float4 q = sp[i];
            comb(m, z, w, s, q.x, q.y, q.z, q.w);
        }
        partials[blockIdx.x] = make_float4(m, z, w, s);
        __threadfence();                      // release partials (agent scope)
        unsigned int v = atomicAdd(counter, 1u);
        isLast = (v == (unsigned int)(gridDim.x - 1));
    }
    __syncthreads();

    if (!isLast) return;

    // ---- final reduction by the last block (replaces k_fin) ----
    __threadfence();                          // acquire all blocks' partials
    float fm = -INFINITY, fz = 0.0f, fw = 0.0f, fs = 0.0f;
    for (int i = threadIdx.x; i < (int)gridDim.x; i += NTHR) {
        float4 q = partials[i];
        comb(fm, fz, fw, fs, q.x, q.y, q.z, q.w);
    }
#pragma unroll
    for (int o = 32; o; o >>= 1) {
        float m2 = __shfl_xor(fm, o), z2 = __shfl_xor(fz, o);
        float w2 = __shfl_xor(fw, o), s2 = __shfl_xor(fs, o);
        comb(fm, fz, fw, fs, m2, z2, w2, s2);
    }
    __syncthreads();                          // sp reuse
    if (lane == 0) sp[wid] = make_float4(fm, fz, fw, fs);
    __syncthreads();
    if (threadIdx.x == 0) {
        for (int i = 1; i < (NTHR >> 6); i++) {
            float4 q = sp[i];
            comb(fm, fz, fw, fs, q.x, q.y, q.z, q.w);
        }
        out[0] = fs - fw / fz;
    }
}

extern "C" void kernel_launch(void* const* d_in, const int* in_sizes, int n_in,
                              void* d_out, int out_size, void* d_ws, size_t ws_size,
                              hipStream_t stream) {
    const int*   lca    = (const int*)d_in[0];
    const int*   li     = (const int*)d_in[1];
    const int*   ri     = (const int*)d_in[2];
    const float* sims   = (const float*)d_in[3];
    const float* emb    = (const float*)d_in[4];
    const float* leaves = (const float*)d_in[5];
    const float* scale  = (const float*)d_in[6];
    float* out = (float*)d_out;

    int P       = in_sizes[1];
    int nLeaves = in_sizes[5] / RANK;

    char* ws = (char*)d_ws;
    // layout: D[nLeaves] | partials[NBLK_PAIR] | counter (16B-aligned)
    float*  D        = (float*)ws;
    size_t  poff     = (((size_t)nLeaves * sizeof(float) + 1023) / 1024) * 1024;
    float4* partials = (float4*)(ws + poff);
    unsigned int* counter = (unsigned int*)(ws + poff + (size_t)NBLK_PAIR * sizeof(float4));

    k_leaf<<<2048, NTHR, 0, stream>>>(emb, lca, scale, (const float4*)leaves,
                                      D, nLeaves, counter);
    k_pair<<<NBLK_PAIR, NTHR, 0, stream>>>(li, ri, sims, D, partials, P, counter, out);
}

// Round 3
// 195.447 us; speedup vs baseline: 3.1253x; 1.0727x over previous
//
#include <hip/hip_runtime.h>
#include <math.h>

#define RANK 128
#define INV_T 20.0f      // 1 / 0.05
#define EPS_ARG 1e-7f
#define NBLK_PAIR 512
#define NTHR 256

// online-softmax combine: state (m, z, w); s is a plain sum
__device__ inline void comb(float& m, float& z, float& w, float& s,
                            float m2, float z2, float w2, float s2) {
    float mn = fmaxf(m, m2);
    float a = (m  == mn) ? 1.0f : __expf(m  - mn);
    float b = (m2 == mn) ? 1.0f : __expf(m2 - mn);
    z = z * a + z2 * b;
    w = w * a + w2 * b;
    m = mn;
    s += s2;
}

// ---------------- k_leaf: e1 prep (per-block, redundant) + per-leaf distance ----
__global__ void k_leaf(const float* __restrict__ emb, const int* __restrict__ lca,
                       const float* __restrict__ scale,
                       const float4* __restrict__ leaves,
                       float* __restrict__ D, int nLeaves) {
    __shared__ float4 se1[RANK / 4];
    __shared__ float  snx[2];
    int t = threadIdx.x;

    // ---- per-block e1 normalization (512B broadcast read, 1 half-wave) ----
    if (t < 32) {
        float4 v = ((const float4*)(emb + (size_t)lca[0] * RANK))[t];
        float sq = v.x * v.x + v.y * v.y + v.z * v.z + v.w * v.w;
#pragma unroll
        for (int o = 16; o; o >>= 1) sq += __shfl_down(sq, o, 32);
        sq = __shfl(sq, 0, 32);
        float bn = sqrtf(sq);
        float s = fminf(fmaxf(scale[0], 0.01f), 1.0f - 0.001f);
        float k = s / fmaxf(bn, 1e-12f);
        float4 e; e.x = v.x * k; e.y = v.y * k; e.z = v.z * k; e.w = v.w * k;
        se1[t] = e;
        float sq2 = e.x * e.x + e.y * e.y + e.z * e.z + e.w * e.w;
#pragma unroll
        for (int o = 16; o; o >>= 1) sq2 += __shfl_down(sq2, o, 32);
        if (t == 0) {
            snx[0] = sq2;                  // nx
            snx[1] = 1.0f / (1.0f - sq2);  // 1/(1-nx)
        }
    }
    __syncthreads();

    // ---- leaf distances: one wave = 2 leaves, float4/lane coalesced ----
    int lane = t & 63, wid = t >> 6;
    int l31 = lane & 31, half = lane >> 5;
    int wavesPerBlock = NTHR >> 6;
    int gw = blockIdx.x * wavesPerBlock + wid;
    int nw = gridDim.x * wavesPerBlock;
    float nx = snx[0], invdx = snx[1];
    float4 e = se1[l31];
    for (int jj = gw; 2 * jj < nLeaves; jj += nw) {
        int j = 2 * jj + half;
        float dot = 0.0f, ny = 0.0f;
        if (j < nLeaves) {
            float4 y = leaves[(size_t)j * (RANK / 4) + l31];   // 1KB/wave
            dot = y.x * e.x + y.y * e.y + y.z * e.z + y.w * e.w;
            ny  = y.x * y.x + y.y * y.y + y.z * y.z + y.w * y.w;
        }
#pragma unroll
        for (int o = 16; o; o >>= 1) {
            dot += __shfl_down(dot, o, 32);
            ny  += __shfl_down(ny, o, 32);
        }
        if (l31 == 0 && j < nLeaves) {
            float sq  = nx + ny - 2.0f * dot;                  // ||x-y||^2
            float arg = 1.0f + 2.0f * sq * invdx / (1.0f - ny);
            arg = fmaxf(arg, 1.0f + EPS_ARG);
            D[j] = acoshf(arg);
        }
    }
}

// ---------------- k_pair: fused pair online-softmax partials (no fences) ----
__global__ void k_pair(const int* __restrict__ li, const int* __restrict__ ri,
                       const float* __restrict__ sims, const float* __restrict__ D,
                       float4* __restrict__ partials, int P) {
    float m = -INFINITY, z = 0.0f, w = 0.0f, s = 0.0f;
    int tid = blockIdx.x * NTHR + threadIdx.x;
    int nthreads = gridDim.x * NTHR;
    int P4 = P >> 2;
    const int4*   li4 = (const int4*)li;
    const int4*   ri4 = (const int4*)ri;
    const float4* s4p = (const float4*)sims;
    for (int i = tid; i < P4; i += nthreads) {
        int4 l = li4[i], r = ri4[i];
        float4 sv = s4p[i];
        float a0 = D[l.x], b0 = D[r.x];
        float a1 = D[l.y], b1 = D[r.y];
        float a2 = D[l.z], b2 = D[r.z];
        float a3 = D[l.w], b3 = D[r.w];
        float t0 = (a0 + b0) * INV_T, t1 = (a1 + b1) * INV_T;
        float t2 = (a2 + b2) * INV_T, t3 = (a3 + b3) * INV_T;
#define STEP(tp, svv)                                                  \
        if (tp <= m) { float e = __expf(tp - m); z += e; w = fmaf(svv, e, w); } \
        else { float rr = __expf(m - tp); z = fmaf(z, rr, 1.0f); w = fmaf(w, rr, svv); m = tp; } \
        s += svv;
        STEP(t0, sv.x) STEP(t1, sv.y) STEP(t2, sv.z) STEP(t3, sv.w)
    }
    int tail0 = P4 << 2;
    for (int p = tail0 + tid; p < P; p += nthreads) {
        float tp = (D[li[p]] + D[ri[p]]) * INV_T;
        float svv = sims[p];
        STEP(tp, svv)
    }
#undef STEP
#pragma unroll
    for (int o = 32; o; o >>= 1) {
        float m2 = __shfl_xor(m, o), z2 = __shfl_xor(z, o);
        float w2 = __shfl_xor(w, o), s2 = __shfl_xor(s, o);
        comb(m, z, w, s, m2, z2, w2, s2);
    }
    __shared__ float4 sp[NTHR / 64];
    int lane = threadIdx.x & 63, wid = threadIdx.x >> 6;
    if (lane == 0) sp[wid] = make_float4(m, z, w, s);
    __syncthreads();
    if (threadIdx.x == 0) {
        for (int i = 1; i < (NTHR >> 6); i++) {
            float4 q = sp[i];
            comb(m, z, w, s, q.x, q.y, q.z, q.w);
        }
        partials[blockIdx.x] = make_float4(m, z, w, s);
    }
}

// ---------------- k_fin: reduce per-block partials ----------------
__global__ void k_fin(const float4* __restrict__ partials, float* __restrict__ out, int nb) {
    int t = threadIdx.x;               // 256 threads
    float m = -INFINITY, z = 0.0f, w = 0.0f, s = 0.0f;
    for (int i = t; i < nb; i += blockDim.x) {
        float4 q = partials[i];
        comb(m, z, w, s, q.x, q.y, q.z, q.w);
    }
#pragma unroll
    for (int o = 32; o; o >>= 1) {
        float m2 = __shfl_xor(m, o), z2 = __shfl_xor(z, o);
        float w2 = __shfl_xor(w, o), s2 = __shfl_xor(s, o);
        comb(m, z, w, s, m2, z2, w2, s2);
    }
    __shared__ float4 sp[4];
    int lane = t & 63, wid = t >> 6;
    if (lane == 0) sp[wid] = make_float4(m, z, w, s);
    __syncthreads();
    if (t == 0) {
        for (int i = 1; i < (int)(blockDim.x >> 6); i++) {
            float4 q = sp[i];
            comb(m, z, w, s, q.x, q.y, q.z, q.w);
        }
        out[0] = s - w / z;
    }
}

extern "C" void kernel_launch(void* const* d_in, const int* in_sizes, int n_in,
                              void* d_out, int out_size, void* d_ws, size_t ws_size,
                              hipStream_t stream) {
    const int*   lca    = (const int*)d_in[0];
    const int*   li     = (const int*)d_in[1];
    const int*   ri     = (const int*)d_in[2];
    const float* sims   = (const float*)d_in[3];
    const float* emb    = (const float*)d_in[4];
    const float* leaves = (const float*)d_in[5];
    const float* scale  = (const float*)d_in[6];
    float* out = (float*)d_out;

    int P       = in_sizes[1];
    int nLeaves = in_sizes[5] / RANK;

    char* ws = (char*)d_ws;
    // layout: D[nLeaves] | partials[NBLK_PAIR] (16B-aligned)
    float*  D        = (float*)ws;
    size_t  poff     = (((size_t)nLeaves * sizeof(float) + 1023) / 1024) * 1024;
    float4* partials = (float4*)(ws + poff);

    k_leaf<<<2048, NTHR, 0, stream>>>(emb, lca, scale, (const float4*)leaves, D, nLeaves);
    k_pair<<<NBLK_PAIR, NTHR, 0, stream>>>(li, ri, sims, D, partials, P);
    k_fin <<<1, NTHR, 0, stream>>>(partials, out, NBLK_PAIR);
}